// Round 7
// baseline (343.947 us; speedup 1.0000x reference)
//
#include <hip/hip_runtime.h>

#define NB 16
#define NN 300000
#define PRE 2000
#define POST 1000

typedef unsigned long long ull;

// ---------- workspace layout (bytes) ----------
static const size_t OFF_HIST1   = 0;                       // 16*1024*4 = 65536
static const size_t OFF_STASHC  = 65536;                   // 64 (pad 256)
static const size_t OFF_NVALID  = 66560;
static const size_t OFF_BITMAP  = 66816;                   // 16*32*8 = 4096
static const size_t ZERO_BYTES  = 70912;                   // memset region
static const size_t OFF_CAND    = 70912;                   // 16*2048*4 = 131072
static const size_t OFF_KEYS    = 201984;                  // 16*2048*8 = 262144
static const size_t OFF_BOXTMP  = 464128;                  // 16*2048*16 = 524288
static const size_t OFF_SORTED  = 988416;                  // 16*2000*16 = 512000
static const size_t OFF_MASK    = 1500416;                 // 16*2000*32*8 = 8192000 (end 9692416)
static const size_t OFF_STASH   = OFF_MASK;                // ALIAS: 16*32768*8 = 4MB, consumed by k_select
                                                           // before k_mask writes masks (serial stream)

#define BSTAT 767u       // bin of 1.5f: stash covers all bins >= 767; threshold bin is 768 (~2.17 sigma)
#define STCAP 32768u     // expected ~20K/img (P(x>=1.5)=6.7%), cap = +93 sigma

__device__ __forceinline__ unsigned f2u(float f){
  unsigned b = __float_as_uint(f);
  return (b & 0x80000000u) ? ~b : (b | 0x80000000u);
}

// ---------- fused pass: 10-bit histogram (8 replicated LDS copies) + stash of (u,i) for u>>22 >= BSTAT ----------
#define H1REP 8
#define H1STRIDE 1025
__global__ void k_histstash(const float* __restrict__ cls, unsigned* __restrict__ hist,
                            ull* __restrict__ stash, unsigned* __restrict__ stashCnt){
  __shared__ unsigned h[H1REP * H1STRIDE];
  __shared__ ull lb[512];
  __shared__ unsigned lbn, baseB;
  int img = blockIdx.y;
  for (int i = threadIdx.x; i < H1REP * H1STRIDE; i += blockDim.x) h[i] = 0;
  if (threadIdx.x == 0) lbn = 0;
  __syncthreads();
  const float* p = cls + (size_t)img * NN;
  int stride = gridDim.x * blockDim.x;
  unsigned rep = (threadIdx.x & (H1REP - 1)) * H1STRIDE;
  ull* st = stash + (size_t)img * STCAP;
  for (int i = blockIdx.x * blockDim.x + threadIdx.x; i < NN; i += stride){
    unsigned u = f2u(p[i]);
    atomicAdd(&h[rep + (u >> 22)], 1u);
    if ((u >> 22) >= BSTAT){
      ull e = ((ull)u << 32) | (unsigned)i;
      unsigned pos = atomicAdd(&lbn, 1u);
      if (pos < 512u) lb[pos] = e;
      else { unsigned g = atomicAdd(&stashCnt[img], 1u); if (g < STCAP) st[g] = e; }
    }
  }
  __syncthreads();
  unsigned nb = lbn < 512u ? lbn : 512u;
  if (threadIdx.x == 0 && nb) baseB = atomicAdd(&stashCnt[img], nb);
  __syncthreads();
  for (unsigned t = threadIdx.x; t < nb; t += blockDim.x){
    unsigned g = baseB + t;
    if (g < STCAP) st[g] = lb[t];
  }
  unsigned* g = hist + img * 1024;
  for (int i = threadIdx.x; i < 1024; i += blockDim.x){
    unsigned v = 0;
    for (int r = 0; r < H1REP; r++) v += h[r * H1STRIDE + i];
    if (v) atomicAdd(&g[i], v);
  }
}

// ---------- one block per image: rank-select prologue + 2-level in-LDS refinement
//            over the stash + tie-rank + fused decode/clip/key ----------
__global__ __launch_bounds__(256) void k_select(const float* __restrict__ cls,
                                                const float* __restrict__ reg,
                                                const float* __restrict__ anch,
                                                const unsigned* __restrict__ hist1,
                                                unsigned* __restrict__ cand,
                                                const ull* __restrict__ stash,
                                                const unsigned* __restrict__ stashCnt,
                                                float* __restrict__ boxTmp,
                                                ull* __restrict__ keys,
                                                unsigned* __restrict__ nvalid){
  __shared__ unsigned hist[2048];
  __shared__ unsigned arr[256];
  __shared__ unsigned b1s, need1s, b2s, need2s, b3s, need3s;
  __shared__ unsigned tiePos[1024];
  __shared__ unsigned wcnt, tieCnt;
  int img = blockIdx.x, tid = threadIdx.x;
  const float* pcls = cls + (size_t)img * NN;
  const ull* st = stash + (size_t)img * STCAP;

  if (tid == 0){ wcnt = 0; tieCnt = 0; b1s = 0; need1s = 0; b2s = 0; need2s = 0; b3s = 0; need3s = 0; }
  // ---- prologue: descending rank-select over the 1024-bin global histogram (K=2000) ----
  {
    const unsigned* hh = hist1 + img * 1024;
    unsigned s = 0;
    for (int q = 0; q < 4; q++) s += hh[1023 - (tid * 4 + q)];
    arr[tid] = s; __syncthreads();
    for (int off = 1; off < 256; off <<= 1){
      unsigned v = (tid >= off) ? arr[tid - off] : 0u;
      __syncthreads(); arr[tid] += v; __syncthreads();
    }
    unsigned incl = arr[tid], excl = incl - s;
    if (excl < 2000u && 2000u <= incl){
      unsigned c = excl;
      for (int q = 0; q < 4; q++){
        int b = 1023 - (tid * 4 + q);
        unsigned cnt = hh[b];
        if (c + cnt >= 2000u){ b1s = (unsigned)b; need1s = 2000u - c; break; }
        c += cnt;
      }
    }
  }
  // zero refinement hist while the prologue result settles
  for (int i = tid; i < 2048; i += 256) hist[i] = 0;
  __syncthreads();
  unsigned b1 = b1s, need = need1s;
  unsigned sc = stashCnt[img];
  bool fb = (b1 < BSTAT) || (sc > STCAP);     // stash insufficient -> full rescan (never for this data)
  unsigned Nit = fb ? (unsigned)NN : sc;

  // ---- pass A: top>b1 -> cand (slots [0,above)); top==b1 -> hist of bits 21..11 ----
  for (unsigned t = tid; t < Nit; t += 256){
    unsigned u, idx;
    if (fb){ u = f2u(pcls[t]); idx = t; }
    else { ull e = st[t]; u = (unsigned)(e >> 32); idx = (unsigned)(e & 0xFFFFFFFFull); }
    unsigned top = u >> 22;
    if (top > b1){
      unsigned p = atomicAdd(&wcnt, 1u);
      if (p < 2048u) cand[img * 2048 + p] = idx;
    } else if (top == b1){
      atomicAdd(&hist[(u >> 11) & 0x7FFu], 1u);
    }
  }
  __syncthreads();
  // ---- S1 select (b2, need2) ----
  {
    unsigned s = 0;
    for (int q = 0; q < 8; q++) s += hist[2047 - (tid * 8 + q)];
    arr[tid] = s; __syncthreads();
    for (int off = 1; off < 256; off <<= 1){
      unsigned v = (tid >= off) ? arr[tid - off] : 0u;
      __syncthreads(); arr[tid] += v; __syncthreads();
    }
    unsigned incl = arr[tid], excl = incl - s;
    if (excl < need && need <= incl){
      unsigned c = excl;
      for (int q = 0; q < 8; q++){
        int b = 2047 - (tid * 8 + q);
        unsigned cnt = hist[b];
        if (c + cnt >= need){ b2s = (unsigned)b; need2s = need - c; break; }
        c += cnt;
      }
    }
  }
  __syncthreads();
  unsigned b2 = b2s, need2 = need2s;
  // ---- S2: hist of bits 10..0 where top==b1 && mid==b2 ----
  for (int i = tid; i < 2048; i += 256) hist[i] = 0;
  __syncthreads();
  for (unsigned t = tid; t < Nit; t += 256){
    unsigned u;
    if (fb) u = f2u(pcls[t]);
    else u = (unsigned)(st[t] >> 32);
    if ((u >> 22) == b1 && ((u >> 11) & 0x7FFu) == b2) atomicAdd(&hist[u & 0x7FFu], 1u);
  }
  __syncthreads();
  {
    unsigned s = 0;
    for (int q = 0; q < 8; q++) s += hist[2047 - (tid * 8 + q)];
    arr[tid] = s; __syncthreads();
    for (int off = 1; off < 256; off <<= 1){
      unsigned v = (tid >= off) ? arr[tid - off] : 0u;
      __syncthreads(); arr[tid] += v; __syncthreads();
    }
    unsigned incl = arr[tid], excl = incl - s;
    if (excl < need2 && need2 <= incl){
      unsigned c = excl;
      for (int q = 0; q < 8; q++){
        int b = 2047 - (tid * 8 + q);
        unsigned cnt = hist[b];
        if (c + cnt >= need2){ b3s = (unsigned)b; need3s = need2 - c; break; }
        c += cnt;
      }
    }
  }
  __syncthreads();
  unsigned b3 = b3s, need3 = need3s;
  // ---- S3: takes (continue wcnt), collect ties ----
  for (unsigned t = tid; t < Nit; t += 256){
    unsigned u, idx;
    if (fb){ u = f2u(pcls[t]); idx = t; }
    else { ull e = st[t]; u = (unsigned)(e >> 32); idx = (unsigned)(e & 0xFFFFFFFFull); }
    if ((u >> 22) != b1) continue;
    unsigned mid = (u >> 11) & 0x7FFu, low = u & 0x7FFu;
    bool take = (mid > b2) || (mid == b2 && low > b3);
    bool tie  = (mid == b2) && (low == b3);
    if (take){
      unsigned p = atomicAdd(&wcnt, 1u);
      if (p < 2048u) cand[img * 2048 + p] = idx;
    } else if (tie){
      unsigned p = atomicAdd(&tieCnt, 1u);
      if (p < 1024u) tiePos[p] = t;
    }
  }
  __syncthreads();
  unsigned tbase = wcnt;                 // == 2000 - need3
  unsigned ec = tieCnt; if (ec > 1024u) ec = 1024u;
  // rank ties by index asc, keep the need3 smallest (order within cand irrelevant: keys fix it)
  for (unsigned t = tid; t < ec; t += 256){
    unsigned idx = fb ? tiePos[t] : (unsigned)(st[tiePos[t]] & 0xFFFFFFFFull);
    unsigned r = 0;
    for (unsigned s = 0; s < ec; s++){
      unsigned idx2 = fb ? tiePos[s] : (unsigned)(st[tiePos[s]] & 0xFFFFFFFFull);
      r += (idx2 < idx) ? 1u : 0u;
    }
    if (r < need3){
      unsigned g = tbase + r;
      if (g < 2048u) cand[img * 2048 + g] = idx;
    }
  }
  __syncthreads();
  // ---- fused decode + clip + validity + key for all 2048 slots of this image ----
  for (int slot = tid; slot < 2048; slot += 256){
    ull key = 0ull;
    float4 box = make_float4(0.f, 0.f, 0.f, 0.f);
    bool counted = false;
    if (slot < PRE){
      unsigned i = cand[img * 2048 + slot];
      if (i < NN){
        size_t gi = (size_t)img * NN + i;
        float4 a = ((const float4*)anch)[gi];
        float4 r = ((const float4*)reg)[gi];
        float sc2 = cls[gi];
        float aw = a.z - a.x, ah = a.w - a.y;
        float acx = a.x + 0.5f * aw, acy = a.y + 0.5f * ah;
        float pcx = r.x * aw + acx, pcy = r.y * ah + acy;
        float pw = expf(r.z) * aw, ph = expf(r.w) * ah;
        float x1 = pcx - 0.5f * pw, y1 = pcy - 0.5f * ph;
        float x2 = pcx + 0.5f * pw, y2 = pcy + 0.5f * ph;
        x1 = fminf(fmaxf(x1, 0.f), 1333.f); x2 = fminf(fmaxf(x2, 0.f), 1333.f);
        y1 = fminf(fmaxf(y1, 0.f), 800.f);  y2 = fminf(fmaxf(y2, 0.f), 800.f);
        bool valid = ((x2 - x1) >= 0.001f) && ((y2 - y1) >= 0.001f);
        unsigned up = valid ? f2u(sc2) : 0u;
        key = ((ull)up << 32) | (ull)(0xFFFFFFFFu - i);   // score desc, index asc
        box = make_float4(x1, y1, x2, y2);
        counted = valid;
      }
    }
    keys[img * 2048 + slot] = key;
    ((float4*)boxTmp)[img * 2048 + slot] = box;
    ull bal = __ballot(counted);
    if ((tid & 63) == 0 && bal)
      atomicAdd(&nvalid[img], (unsigned)__popcll(bal));
  }
}

// ---------- rank-by-counting sort: rank = #{j : key_j > key_e}; scatter ----------
__global__ __launch_bounds__(256) void k_rank(const ull* __restrict__ keys,
                                              const float* __restrict__ boxTmp,
                                              float* __restrict__ sorted){
  __shared__ ull lk[2048];
  int img = blockIdx.y;
  int e = blockIdx.x * 256 + threadIdx.x;
  for (int t = threadIdx.x; t < 2048; t += 256) lk[t] = keys[img * 2048 + t];
  __syncthreads();
  ull me = lk[e];
  unsigned rank = 0;
  #pragma unroll 8
  for (int j = 0; j < 2048; j++) rank += (lk[j] > me) ? 1u : 0u;
  if (rank < PRE)
    ((float4*)sorted)[img * PRE + rank] = ((const float4*)boxTmp)[img * 2048 + e];
}

// ---------- suppression bitmask, PERMUTED layout: word w bit q <-> j = 32q+w ----------
// Triangular load balance (R6, verified): unit owns front row f and mirror PRE-1-f,
// constant ~63 q-iters/unit. Grid 63x16 ~ 4 blocks/CU (LDS limit), uniform drain.
__global__ __launch_bounds__(512) void k_mask(const float* __restrict__ sorted,
                                              const unsigned* __restrict__ nvalid,
                                              ull* __restrict__ mask, ull* __restrict__ bitmap){
  __shared__ float4 bx[PRE];
  __shared__ float  ar[PRE];
  int img = blockIdx.y, tid = threadIdx.x;
  int jmin = blockIdx.x * 16;
  for (int i = jmin + tid; i < PRE; i += 512){
    float4 b = ((const float4*)sorted)[img * PRE + i];
    bx[i] = b;
    ar[i] = (b.z - b.x) * (b.w - b.y);
  }
  __syncthreads();
  int unit = tid >> 5;                       // 0..15
  int w = tid & 31;
  int lane = tid & 63;
  int nv = (int)nvalid[img];
  int qhi = ((PRE - 1 - w) >> 5) + 1;
  int rowF = jmin + unit;                    // front row in [0, 1008)
  #pragma unroll
  for (int rr = 0; rr < 2; rr++){
    int row = (rr == 0) ? rowF : (PRE - 1 - rowF);   // mirror pair (middle overlap benign)
    float4 bi = bx[row];
    float ai = ar[row];
    int qlo = (row >= w) ? (((row - w) >> 5) + 1) : 0;
    ull m = 0;
    #pragma unroll 2
    for (int q = qlo; q < qhi; q++){
      int j = (q << 5) + w;
      float4 bj = bx[j];
      float xx1 = fmaxf(bi.x, bj.x), yy1 = fmaxf(bi.y, bj.y);
      float xx2 = fminf(bi.z, bj.z), yy2 = fminf(bi.w, bj.w);
      float ww = fmaxf(xx2 - xx1, 0.f), hh = fmaxf(yy2 - yy1, 0.f);
      float inter = ww * hh;
      float uni = ai + ar[j] - inter;
      if (inter / fmaxf(uni, 1e-8f) > 0.7f) m |= (1ull << q);   // exact div (bit-match)
    }
    mask[((size_t)(img * PRE + row)) * 32 + w] = m;
    ull nz = __ballot(m != 0ull);            // wave = 2 units; halves are per-unit rows
    if (lane == 0 || lane == 32){
      ull half = (lane == 0) ? (nz & 0xFFFFFFFFull) : (nz >> 32);
      if (half && row < nv)
        atomicOr(&bitmap[img * 32 + (row >> 6)], 1ull << (row & 63));
    }
  }
}

// ---------- serial NMS scan (latency-optimized) + rank/scatter + zero-fill tail ----------
#define CHR 48
__global__ __launch_bounds__(256) void k_nms(const ull* __restrict__ mask,
                                             const ull* __restrict__ bitmap,
                                             const unsigned* __restrict__ nvalid,
                                             const float* __restrict__ sorted,
                                             float* __restrict__ out){
  __shared__ unsigned rowsLds[2048];
  __shared__ unsigned cntw[32];
  __shared__ unsigned wbaseS[32];
  __shared__ int mcountS, mpS;
  __shared__ ull cacheD[2][CHR * 32];
  __shared__ ull keepP[32];     // permuted keep: word w bit q -> j = 32q+w
  __shared__ ull keepLin[32];   // linear keep:   word w bit b -> i = 64w+b
  __shared__ unsigned cntArr[32], preArr[32];
  int img = blockIdx.x, tid = threadIdx.x;
  int lane = tid & 63, wave = tid >> 6;

  // ---- phase A: parallel ordered row-list build ----
  if (tid < 32) cntw[tid] = (unsigned)__popcll(bitmap[img * 32 + tid]);
  __syncthreads();
  if (tid == 0){
    unsigned s = 0;
    for (int w0 = 0; w0 < 32; w0++){ wbaseS[w0] = s; s += cntw[w0]; }
    mcountS = (int)s;
    mpS = ((int)s + CHR - 1) / CHR * CHR;
  }
  __syncthreads();
  int m = mcountS, mp = mpS;
  if (tid < 32){
    ull bits = bitmap[img * 32 + tid];
    unsigned pos = wbaseS[tid];
    int base_i = tid * 64;
    while (bits){
      int b = __ffsll((long long)bits) - 1;
      rowsLds[pos++] = (unsigned)(base_i + b);
      bits &= bits - 1;
    }
  }
  for (int t = m + tid; t < mp; t += 256) rowsLds[t] = PRE - 1;  // zero-mask pad row
  __syncthreads();

  // ---- phase B: double-buffered staged serial scan ----
  int nch = mp / CHR;
  ull remv = 0;
  const ull* mg = mask + (size_t)img * PRE * 32;

  if (nch > 0 && tid >= 64){
    int s = tid - 64;
    ull v[8];
    #pragma unroll
    for (int k = 0; k < 8; k++){
      int t = k * 192 + s;                 // 0..1535 = 48 rows * 32 words
      unsigned rr = rowsLds[t >> 5];
      v[k] = mg[(size_t)rr * 32 + (t & 31)];
    }
    #pragma unroll
    for (int k = 0; k < 8; k++) cacheD[0][k * 192 + s] = v[k];
  }
  __syncthreads();

  for (int c = 0; c < nch; c++){
    int cb = c & 1;
    if (tid >= 64){
      if (c + 1 < nch){
        int q0n = (c + 1) * CHR;
        int s = tid - 64;
        ull v[8];
        #pragma unroll
        for (int k = 0; k < 8; k++){
          int t = k * 192 + s;
          unsigned rr = rowsLds[q0n + (t >> 5)];
          v[k] = mg[(size_t)rr * 32 + (t & 31)];
        }
        #pragma unroll
        for (int k = 0; k < 8; k++) cacheD[cb ^ 1][k * 192 + s] = v[k];
      }
    } else {
      // wave 0: serial scan of 48 rows, pipelined 8 ahead
      const ull* cbuf = cacheD[cb];
      const int q0 = c * CHR;
      ull cur[8]; unsigned ci[8];
      #pragma unroll
      for (int k = 0; k < 8; k++){
        ci[k] = rowsLds[q0 + k];
        cur[k] = cbuf[(k << 5) | (lane & 31)];
      }
      #pragma unroll
      for (int g = 0; g < 6; g++){
        ull nxt[8]; unsigned ni[8];
        if (g < 5){
          #pragma unroll
          for (int k = 0; k < 8; k++){
            int lq = (g + 1) * 8 + k;
            ni[k] = rowsLds[q0 + lq];
            nxt[k] = cbuf[(lq << 5) | (lane & 31)];
          }
        }
        #pragma unroll
        for (int k = 0; k < 8; k++){
          unsigned i = ci[k];
          unsigned bit = ((unsigned)(remv >> (i >> 5))) & 1u;
          int sup = (lane == (int)(i & 31)) && bit;
          if (!__any(sup)) remv |= cur[k];
        }
        if (g < 5){
          #pragma unroll
          for (int k = 0; k < 8; k++){ cur[k] = nxt[k]; ci[k] = ni[k]; }
        }
      }
    }
    __syncthreads();
  }

  // ---- epilogue: keep mask -> compaction + zero-fill tail ----
  int nv = (int)nvalid[img];
  if (wave == 0 && lane < 32){
    int cnt2 = (nv > lane) ? (((nv - 1 - lane) >> 5) + 1) : 0;   // #valid q for this word
    ull vm = (cnt2 >= 64) ? ~0ull : ((1ull << cnt2) - 1ull);
    keepP[lane] = (~remv) & vm;
  }
  __syncthreads();
  if (tid < 32){   // permuted -> linear
    ull lin = 0;
    for (int kk = 0; kk < 64; kk++)
      lin |= ((keepP[kk & 31] >> (2 * tid + (kk >> 5))) & 1ull) << kk;
    keepLin[tid] = lin;
    cntArr[tid] = (unsigned)__popcll(lin);
  }
  __syncthreads();
  if (tid < 32){
    unsigned pre = 0;
    for (int w0 = 0; w0 < tid; w0++) pre += cntArr[w0];
    preArr[tid] = pre;
  }
  __syncthreads();
  int totK = (int)(preArr[31] + cntArr[31]);   // total kept
  for (int i = tid; i < PRE; i += 256){
    int w0 = i >> 6, b = i & 63;
    ull kw = keepLin[w0];
    if ((kw >> b) & 1ull){
      unsigned rank = preArr[w0] + (unsigned)__popcll(kw & ((1ull << b) - 1ull));
      if (rank < POST)
        ((float4*)out)[img * POST + rank] = ((const float4*)sorted)[img * PRE + i];
    }
  }
  for (int r = totK + tid; r < POST; r += 256)
    ((float4*)out)[img * POST + r] = make_float4(0.f, 0.f, 0.f, 0.f);
}

extern "C" void kernel_launch(void* const* d_in, const int* in_sizes, int n_in,
                              void* d_out, int out_size, void* d_ws, size_t ws_size,
                              hipStream_t stream){
  const float* cls  = (const float*)d_in[0];
  const float* reg  = (const float*)d_in[1];
  const float* anch = (const float*)d_in[2];
  float* out = (float*)d_out;
  char* ws = (char*)d_ws;

  unsigned* hist1    = (unsigned*)(ws + OFF_HIST1);
  unsigned* stashCnt = (unsigned*)(ws + OFF_STASHC);
  unsigned* nvalid   = (unsigned*)(ws + OFF_NVALID);
  ull*      bitmap   = (ull*)     (ws + OFF_BITMAP);
  unsigned* cand     = (unsigned*)(ws + OFF_CAND);
  ull*      keys     = (ull*)     (ws + OFF_KEYS);
  float*    boxTmp   = (float*)   (ws + OFF_BOXTMP);
  float*    sorted   = (float*)   (ws + OFF_SORTED);
  ull*      maskG    = (ull*)     (ws + OFF_MASK);
  ull*      stash    = (ull*)     (ws + OFF_STASH);

  hipMemsetAsync(ws, 0, ZERO_BYTES, stream);

  k_histstash<<<dim3(64, NB), 256, 0, stream>>>(cls, hist1, stash, stashCnt);
  k_select   <<<NB, 256, 0, stream>>>(cls, reg, anch, hist1, cand, stash, stashCnt,
                                      boxTmp, keys, nvalid);
  k_rank     <<<dim3(8, NB), 256, 0, stream>>>(keys, boxTmp, sorted);
  k_mask     <<<dim3(63, NB), 512, 0, stream>>>(sorted, nvalid, maskG, bitmap);
  k_nms      <<<NB, 256, 0, stream>>>(maskG, bitmap, nvalid, sorted, out);
}

// Round 8
// 320.813 us; speedup vs baseline: 1.0721x; 1.0721x over previous
//
#include <hip/hip_runtime.h>

#define NB 16
#define NN 300000
#define PRE 2000
#define POST 1000

typedef unsigned long long ull;

// ---------- workspace layout (bytes) ----------
static const size_t OFF_HIST1   = 0;                       // 16*1024*4 = 65536
static const size_t OFF_STASHC  = 65536;                   // 64 (pad 256)
static const size_t OFF_CANDCNT = 65792;
static const size_t OFF_BINCNT  = 66048;
static const size_t OFF_B1      = 66304;
static const size_t OFF_NEED1   = 66560;
static const size_t OFF_NVALID  = 66816;
static const size_t OFF_BITMAP  = 67072;                   // 16*32*8 = 4096
static const size_t ZERO_BYTES  = 71168;                   // memset region
static const size_t OFF_CAND    = 71168;                   // 16*2048*4 = 131072
static const size_t OFF_KEYS    = 202240;                  // 16*2048*8 = 262144
static const size_t OFF_BOXTMP  = 464384;                  // 16*2048*16 = 524288
static const size_t OFF_SORTED  = 988672;                  // 16*2000*16 = 512000
static const size_t OFF_MASK    = 1500672;                 // 16*2000*32*8 = 8192000 (end 9692672)
static const size_t OFF_STASH   = OFF_MASK;                // ALIAS: 16*32768*8 = 4MB
static const size_t OFF_BINBUF  = OFF_MASK + 4194304;      // ALIAS: 16*8192*8 = 1MB
// stash+binbuf live inside the mask region and are fully consumed (k_compactS,
// k_select) before k_mask writes masks — stream-serial, no overlap hazard.

#define BSTAT 767u       // bin of 1.5f: stash covers all bins >= 767; threshold bin ~768 (2.17 sigma)
#define STCAP 32768u     // expected ~20K/img (P(x>=1.5)=6.7%), cap = +93 sigma

__device__ __forceinline__ unsigned f2u(float f){
  unsigned b = __float_as_uint(f);
  return (b & 0x80000000u) ? ~b : (b | 0x80000000u);
}

// ---------- fused pass: 10-bit histogram (8 replicated LDS copies) + stash (u,i) for bin >= BSTAT ----------
#define H1REP 8
#define H1STRIDE 1025
__global__ void k_histstash(const float* __restrict__ cls, unsigned* __restrict__ hist,
                            ull* __restrict__ stash, unsigned* __restrict__ stashCnt){
  __shared__ unsigned h[H1REP * H1STRIDE];
  __shared__ ull lb[512];
  __shared__ unsigned lbn, baseB;
  int img = blockIdx.y;
  for (int i = threadIdx.x; i < H1REP * H1STRIDE; i += blockDim.x) h[i] = 0;
  if (threadIdx.x == 0) lbn = 0;
  __syncthreads();
  const float* p = cls + (size_t)img * NN;
  int stride = gridDim.x * blockDim.x;
  unsigned rep = (threadIdx.x & (H1REP - 1)) * H1STRIDE;
  ull* st = stash + (size_t)img * STCAP;
  for (int i = blockIdx.x * blockDim.x + threadIdx.x; i < NN; i += stride){
    unsigned u = f2u(p[i]);
    atomicAdd(&h[rep + (u >> 22)], 1u);
    if ((u >> 22) >= BSTAT){
      ull e = ((ull)u << 32) | (unsigned)i;
      unsigned pos = atomicAdd(&lbn, 1u);
      if (pos < 512u) lb[pos] = e;
      else { unsigned g = atomicAdd(&stashCnt[img], 1u); if (g < STCAP) st[g] = e; }
    }
  }
  __syncthreads();
  unsigned nb = lbn < 512u ? lbn : 512u;
  if (threadIdx.x == 0 && nb) baseB = atomicAdd(&stashCnt[img], nb);
  __syncthreads();
  for (unsigned t = threadIdx.x; t < nb; t += blockDim.x){
    unsigned g = baseB + t;
    if (g < STCAP) st[g] = lb[t];
  }
  unsigned* g = hist + img * 1024;
  for (int i = threadIdx.x; i < 1024; i += blockDim.x){
    unsigned v = 0;
    for (int r = 0; r < H1REP; r++) v += h[r * H1STRIDE + i];
    if (v) atomicAdd(&g[i], v);
  }
}

// ---------- descending rank-select over the 1024-bin histogram ----------
__global__ void k_scan(const unsigned* __restrict__ hist, unsigned K0,
                       unsigned* __restrict__ outBin, unsigned* __restrict__ outNeed){
  int img = blockIdx.x;
  int t = threadIdx.x;
  const unsigned* hh = hist + img * 1024;
  unsigned K = K0;
  unsigned s = 0;
  for (int q = 0; q < 4; q++) s += hh[1023 - (t * 4 + q)];
  __shared__ unsigned arr[256];
  arr[t] = s;
  __syncthreads();
  for (int off = 1; off < 256; off <<= 1){
    unsigned v = (t >= off) ? arr[t - off] : 0u;
    __syncthreads();
    arr[t] += v;
    __syncthreads();
  }
  unsigned incl = arr[t], excl = incl - s;
  if (excl < K && K <= incl){
    unsigned c = excl;
    for (int q = 0; q < 4; q++){
      int b = 1023 - (t * 4 + q);
      unsigned cnt = hh[b];
      if (c + cnt >= K){ outBin[img] = (unsigned)b; outNeed[img] = K - c; break; }
      c += cnt;
    }
  }
}

// ---------- stash compaction: top > b1 -> cand ; top == b1 -> binbuf (LDS-aggregated) ----------
// Reads the ~20K-entry stash (2.6 MB total) instead of the 19.2 MB cls pass.
// Fallback path (stash guard tripped) rescans cls fully — correctness unconditional.
__global__ void k_compactS(const float* __restrict__ cls, const ull* __restrict__ stash,
                           const unsigned* __restrict__ stashCnt, const unsigned* __restrict__ b1,
                           unsigned* __restrict__ cand, unsigned* __restrict__ candCnt,
                           ull* __restrict__ binbuf, unsigned* __restrict__ binCnt){
  __shared__ unsigned lc[1024];
  __shared__ ull lb[512];
  __shared__ unsigned lcn, lbn, baseC, baseB;
  int img = blockIdx.y;
  if (threadIdx.x == 0){ lcn = 0; lbn = 0; }
  __syncthreads();
  unsigned bb1 = b1[img];
  unsigned sc = stashCnt[img];
  bool fb = (bb1 < BSTAT) || (sc > STCAP);
  int stride = gridDim.x * blockDim.x;
  if (!fb){
    const ull* st = stash + (size_t)img * STCAP;
    for (unsigned t = blockIdx.x * blockDim.x + threadIdx.x; t < sc; t += (unsigned)stride){
      ull e = st[t];
      unsigned top = (unsigned)(e >> 54);                  // u>>22 of the high word
      if (top > bb1){
        unsigned pos = atomicAdd(&lcn, 1u);
        if (pos < 1024u) lc[pos] = (unsigned)(e & 0xFFFFFFFFull);
        else { unsigned g = atomicAdd(&candCnt[img], 1u); if (g < 2048u) cand[img * 2048 + g] = (unsigned)(e & 0xFFFFFFFFull); }
      } else if (top == bb1){
        unsigned pos = atomicAdd(&lbn, 1u);
        if (pos < 512u) lb[pos] = e;
        else { unsigned g = atomicAdd(&binCnt[img], 1u); if (g < 8192u) binbuf[img * 8192 + g] = e; }
      }
    }
  } else {
    const float* p = cls + (size_t)img * NN;
    for (int i = blockIdx.x * blockDim.x + threadIdx.x; i < NN; i += stride){
      unsigned u = f2u(p[i]);
      unsigned top = u >> 22;
      if (top > bb1){
        unsigned pos = atomicAdd(&lcn, 1u);
        if (pos < 1024u) lc[pos] = (unsigned)i;
        else { unsigned g = atomicAdd(&candCnt[img], 1u); if (g < 2048u) cand[img * 2048 + g] = (unsigned)i; }
      } else if (top == bb1){
        ull e = ((ull)u << 32) | (unsigned)i;
        unsigned pos = atomicAdd(&lbn, 1u);
        if (pos < 512u) lb[pos] = e;
        else { unsigned g = atomicAdd(&binCnt[img], 1u); if (g < 8192u) binbuf[img * 8192 + g] = e; }
      }
    }
  }
  __syncthreads();
  unsigned nc = lcn < 1024u ? lcn : 1024u;
  unsigned nb = lbn < 512u ? lbn : 512u;
  if (threadIdx.x == 0){
    if (nc) baseC = atomicAdd(&candCnt[img], nc);
    if (nb) baseB = atomicAdd(&binCnt[img], nb);
  }
  __syncthreads();
  for (unsigned t = threadIdx.x; t < nc; t += blockDim.x){
    unsigned g = baseC + t;
    if (g < 2048u) cand[img * 2048 + g] = lc[t];
  }
  for (unsigned t = threadIdx.x; t < nb; t += blockDim.x){
    unsigned g = baseB + t;
    if (g < 8192u) binbuf[img * 8192 + g] = lb[t];
  }
}

// ---------- in-LDS 2-level refinement over bin b1 (~6400 entries) + tie-rank + fused decode ----------
__global__ __launch_bounds__(256) void k_select(const float* __restrict__ cls,
                                                const float* __restrict__ reg,
                                                const float* __restrict__ anch,
                                                unsigned* __restrict__ cand,
                                                const unsigned* __restrict__ candCnt,
                                                const ull* __restrict__ binbuf,
                                                const unsigned* __restrict__ binCnt,
                                                const unsigned* __restrict__ need1,
                                                float* __restrict__ boxTmp,
                                                ull* __restrict__ keys,
                                                unsigned* __restrict__ nvalid){
  __shared__ unsigned hist[2048];
  __shared__ unsigned arr[256];
  __shared__ unsigned b2s, need2s, b3s, need3s;
  __shared__ unsigned tiePos[1024];
  __shared__ unsigned wcnt, tieCnt;
  int img = blockIdx.x, tid = threadIdx.x;
  unsigned bc = binCnt[img]; if (bc > 8192u) bc = 8192u;
  unsigned base = candCnt[img];
  unsigned need = need1[img];
  const ull* bb = binbuf + img * 8192;

  if (tid == 0){ wcnt = 0; tieCnt = 0; b2s = 0; need2s = 0; b3s = 0; need3s = 0; }
  // ---- S1: hist of bits 21..11 ----
  for (int i = tid; i < 2048; i += 256) hist[i] = 0;
  __syncthreads();
  for (unsigned t = tid; t < bc; t += 256){
    unsigned u = (unsigned)(bb[t] >> 32);
    atomicAdd(&hist[(u >> 11) & 0x7FFu], 1u);
  }
  __syncthreads();
  {
    unsigned s = 0;
    for (int q = 0; q < 8; q++) s += hist[2047 - (tid * 8 + q)];
    arr[tid] = s; __syncthreads();
    for (int off = 1; off < 256; off <<= 1){
      unsigned v = (tid >= off) ? arr[tid - off] : 0u;
      __syncthreads(); arr[tid] += v; __syncthreads();
    }
    unsigned incl = arr[tid], excl = incl - s;
    if (excl < need && need <= incl){
      unsigned c = excl;
      for (int q = 0; q < 8; q++){
        int b = 2047 - (tid * 8 + q);
        unsigned cnt = hist[b];
        if (c + cnt >= need){ b2s = (unsigned)b; need2s = need - c; break; }
        c += cnt;
      }
    }
  }
  __syncthreads();
  unsigned b2 = b2s, need2 = need2s;
  // ---- S2: hist of bits 10..0 where mid == b2 ----
  for (int i = tid; i < 2048; i += 256) hist[i] = 0;
  __syncthreads();
  for (unsigned t = tid; t < bc; t += 256){
    unsigned u = (unsigned)(bb[t] >> 32);
    if (((u >> 11) & 0x7FFu) == b2) atomicAdd(&hist[u & 0x7FFu], 1u);
  }
  __syncthreads();
  {
    unsigned s = 0;
    for (int q = 0; q < 8; q++) s += hist[2047 - (tid * 8 + q)];
    arr[tid] = s; __syncthreads();
    for (int off = 1; off < 256; off <<= 1){
      unsigned v = (tid >= off) ? arr[tid - off] : 0u;
      __syncthreads(); arr[tid] += v; __syncthreads();
    }
    unsigned incl = arr[tid], excl = incl - s;
    if (excl < need2 && need2 <= incl){
      unsigned c = excl;
      for (int q = 0; q < 8; q++){
        int b = 2047 - (tid * 8 + q);
        unsigned cnt = hist[b];
        if (c + cnt >= need2){ b3s = (unsigned)b; need3s = need2 - c; break; }
        c += cnt;
      }
    }
  }
  __syncthreads();
  unsigned b3 = b3s, need3 = need3s;
  // ---- S3: write takes, collect ties ----
  for (unsigned t = tid; t < bc; t += 256){
    ull e = bb[t];
    unsigned u = (unsigned)(e >> 32);
    unsigned mid = (u >> 11) & 0x7FFu, low = u & 0x7FFu;
    bool take = (mid > b2) || (mid == b2 && low > b3);
    bool tie  = (mid == b2) && (low == b3);
    if (take){
      unsigned p = atomicAdd(&wcnt, 1u);
      unsigned g = base + p;
      if (g < 2048u) cand[img * 2048 + g] = (unsigned)(e & 0xFFFFFFFFull);
    } else if (tie){
      unsigned p = atomicAdd(&tieCnt, 1u);
      if (p < 1024u) tiePos[p] = t;
    }
  }
  __syncthreads();
  unsigned above = wcnt;                 // == need - need3
  unsigned ec = tieCnt; if (ec > 1024u) ec = 1024u;
  // rank ties by index asc, keep the need3 smallest (order within cand irrelevant: keys fix it)
  for (unsigned t = tid; t < ec; t += 256){
    unsigned idx = (unsigned)(bb[tiePos[t]] & 0xFFFFFFFFull);
    unsigned r = 0;
    for (unsigned s = 0; s < ec; s++){
      unsigned idx2 = (unsigned)(bb[tiePos[s]] & 0xFFFFFFFFull);
      r += (idx2 < idx) ? 1u : 0u;
    }
    if (r < need3){
      unsigned g = base + above + r;
      if (g < 2048u) cand[img * 2048 + g] = idx;
    }
  }
  __syncthreads();
  // ---- fused decode + clip + validity + key for all 2048 slots of this image ----
  for (int slot = tid; slot < 2048; slot += 256){
    ull key = 0ull;
    float4 box = make_float4(0.f, 0.f, 0.f, 0.f);
    bool counted = false;
    if (slot < PRE){
      unsigned i = cand[img * 2048 + slot];
      if (i < NN){
        size_t gi = (size_t)img * NN + i;
        float4 a = ((const float4*)anch)[gi];
        float4 r = ((const float4*)reg)[gi];
        float sc2 = cls[gi];
        float aw = a.z - a.x, ah = a.w - a.y;
        float acx = a.x + 0.5f * aw, acy = a.y + 0.5f * ah;
        float pcx = r.x * aw + acx, pcy = r.y * ah + acy;
        float pw = expf(r.z) * aw, ph = expf(r.w) * ah;
        float x1 = pcx - 0.5f * pw, y1 = pcy - 0.5f * ph;
        float x2 = pcx + 0.5f * pw, y2 = pcy + 0.5f * ph;
        x1 = fminf(fmaxf(x1, 0.f), 1333.f); x2 = fminf(fmaxf(x2, 0.f), 1333.f);
        y1 = fminf(fmaxf(y1, 0.f), 800.f);  y2 = fminf(fmaxf(y2, 0.f), 800.f);
        bool valid = ((x2 - x1) >= 0.001f) && ((y2 - y1) >= 0.001f);
        unsigned up = valid ? f2u(sc2) : 0u;
        key = ((ull)up << 32) | (ull)(0xFFFFFFFFu - i);   // score desc, index asc
        box = make_float4(x1, y1, x2, y2);
        counted = valid;
      }
    }
    keys[img * 2048 + slot] = key;
    ((float4*)boxTmp)[img * 2048 + slot] = box;
    ull bal = __ballot(counted);
    if ((tid & 63) == 0 && bal)
      atomicAdd(&nvalid[img], (unsigned)__popcll(bal));
  }
}

// ---------- rank-by-counting sort: rank = #{j : key_j > key_e}; scatter ----------
__global__ __launch_bounds__(256) void k_rank(const ull* __restrict__ keys,
                                              const float* __restrict__ boxTmp,
                                              float* __restrict__ sorted){
  __shared__ ull lk[2048];
  int img = blockIdx.y;
  int e = blockIdx.x * 256 + threadIdx.x;
  for (int t = threadIdx.x; t < 2048; t += 256) lk[t] = keys[img * 2048 + t];
  __syncthreads();
  ull me = lk[e];
  unsigned rank = 0;
  #pragma unroll 8
  for (int j = 0; j < 2048; j++) rank += (lk[j] > me) ? 1u : 0u;
  if (rank < PRE)
    ((float4*)sorted)[img * PRE + rank] = ((const float4*)boxTmp)[img * 2048 + e];
}

// ---------- suppression bitmask, PERMUTED layout: word w bit q <-> j = 32q+w ----------
// Triangular load balance (R6, verified): unit owns front row f and mirror PRE-1-f,
// constant ~63 q-iters/unit. Grid 63x16 ~ 4 blocks/CU (LDS limit), uniform drain.
__global__ __launch_bounds__(512) void k_mask(const float* __restrict__ sorted,
                                              const unsigned* __restrict__ nvalid,
                                              ull* __restrict__ mask, ull* __restrict__ bitmap){
  __shared__ float4 bx[PRE];
  __shared__ float  ar[PRE];
  int img = blockIdx.y, tid = threadIdx.x;
  int jmin = blockIdx.x * 16;
  for (int i = jmin + tid; i < PRE; i += 512){
    float4 b = ((const float4*)sorted)[img * PRE + i];
    bx[i] = b;
    ar[i] = (b.z - b.x) * (b.w - b.y);
  }
  __syncthreads();
  int unit = tid >> 5;                       // 0..15
  int w = tid & 31;
  int lane = tid & 63;
  int nv = (int)nvalid[img];
  int qhi = ((PRE - 1 - w) >> 5) + 1;
  int rowF = jmin + unit;                    // front row in [0, 1008)
  #pragma unroll
  for (int rr = 0; rr < 2; rr++){
    int row = (rr == 0) ? rowF : (PRE - 1 - rowF);   // mirror pair (middle overlap benign)
    float4 bi = bx[row];
    float ai = ar[row];
    int qlo = (row >= w) ? (((row - w) >> 5) + 1) : 0;
    ull m = 0;
    #pragma unroll 2
    for (int q = qlo; q < qhi; q++){
      int j = (q << 5) + w;
      float4 bj = bx[j];
      float xx1 = fmaxf(bi.x, bj.x), yy1 = fmaxf(bi.y, bj.y);
      float xx2 = fminf(bi.z, bj.z), yy2 = fminf(bi.w, bj.w);
      float ww = fmaxf(xx2 - xx1, 0.f), hh = fmaxf(yy2 - yy1, 0.f);
      float inter = ww * hh;
      float uni = ai + ar[j] - inter;
      if (inter / fmaxf(uni, 1e-8f) > 0.7f) m |= (1ull << q);   // exact div (bit-match)
    }
    mask[((size_t)(img * PRE + row)) * 32 + w] = m;
    ull nz = __ballot(m != 0ull);            // wave = 2 units; halves are per-unit rows
    if (lane == 0 || lane == 32){
      ull half = (lane == 0) ? (nz & 0xFFFFFFFFull) : (nz >> 32);
      if (half && row < nv)
        atomicOr(&bitmap[img * 32 + (row >> 6)], 1ull << (row & 63));
    }
  }
}

// ---------- serial NMS scan (latency-optimized) + rank/scatter + zero-fill tail ----------
#define CHR 48
__global__ __launch_bounds__(256) void k_nms(const ull* __restrict__ mask,
                                             const ull* __restrict__ bitmap,
                                             const unsigned* __restrict__ nvalid,
                                             const float* __restrict__ sorted,
                                             float* __restrict__ out){
  __shared__ unsigned rowsLds[2048];
  __shared__ unsigned cntw[32];
  __shared__ unsigned wbaseS[32];
  __shared__ int mcountS, mpS;
  __shared__ ull cacheD[2][CHR * 32];
  __shared__ ull keepP[32];     // permuted keep: word w bit q -> j = 32q+w
  __shared__ ull keepLin[32];   // linear keep:   word w bit b -> i = 64w+b
  __shared__ unsigned cntArr[32], preArr[32];
  int img = blockIdx.x, tid = threadIdx.x;
  int lane = tid & 63, wave = tid >> 6;

  // ---- phase A: parallel ordered row-list build ----
  if (tid < 32) cntw[tid] = (unsigned)__popcll(bitmap[img * 32 + tid]);
  __syncthreads();
  if (tid == 0){
    unsigned s = 0;
    for (int w0 = 0; w0 < 32; w0++){ wbaseS[w0] = s; s += cntw[w0]; }
    mcountS = (int)s;
    mpS = ((int)s + CHR - 1) / CHR * CHR;
  }
  __syncthreads();
  int m = mcountS, mp = mpS;
  if (tid < 32){
    ull bits = bitmap[img * 32 + tid];
    unsigned pos = wbaseS[tid];
    int base_i = tid * 64;
    while (bits){
      int b = __ffsll((long long)bits) - 1;
      rowsLds[pos++] = (unsigned)(base_i + b);
      bits &= bits - 1;
    }
  }
  for (int t = m + tid; t < mp; t += 256) rowsLds[t] = PRE - 1;  // zero-mask pad row
  __syncthreads();

  // ---- phase B: double-buffered staged serial scan ----
  int nch = mp / CHR;
  ull remv = 0;
  const ull* mg = mask + (size_t)img * PRE * 32;

  if (nch > 0 && tid >= 64){
    int s = tid - 64;
    ull v[8];
    #pragma unroll
    for (int k = 0; k < 8; k++){
      int t = k * 192 + s;                 // 0..1535 = 48 rows * 32 words
      unsigned rr = rowsLds[t >> 5];
      v[k] = mg[(size_t)rr * 32 + (t & 31)];
    }
    #pragma unroll
    for (int k = 0; k < 8; k++) cacheD[0][k * 192 + s] = v[k];
  }
  __syncthreads();

  for (int c = 0; c < nch; c++){
    int cb = c & 1;
    if (tid >= 64){
      if (c + 1 < nch){
        int q0n = (c + 1) * CHR;
        int s = tid - 64;
        ull v[8];
        #pragma unroll
        for (int k = 0; k < 8; k++){
          int t = k * 192 + s;
          unsigned rr = rowsLds[q0n + (t >> 5)];
          v[k] = mg[(size_t)rr * 32 + (t & 31)];
        }
        #pragma unroll
        for (int k = 0; k < 8; k++) cacheD[cb ^ 1][k * 192 + s] = v[k];
      }
    } else {
      // wave 0: serial scan of 48 rows, pipelined 8 ahead
      const ull* cbuf = cacheD[cb];
      const int q0 = c * CHR;
      ull cur[8]; unsigned ci[8];
      #pragma unroll
      for (int k = 0; k < 8; k++){
        ci[k] = rowsLds[q0 + k];
        cur[k] = cbuf[(k << 5) | (lane & 31)];
      }
      #pragma unroll
      for (int g = 0; g < 6; g++){
        ull nxt[8]; unsigned ni[8];
        if (g < 5){
          #pragma unroll
          for (int k = 0; k < 8; k++){
            int lq = (g + 1) * 8 + k;
            ni[k] = rowsLds[q0 + lq];
            nxt[k] = cbuf[(lq << 5) | (lane & 31)];
          }
        }
        #pragma unroll
        for (int k = 0; k < 8; k++){
          unsigned i = ci[k];
          unsigned bit = ((unsigned)(remv >> (i >> 5))) & 1u;
          int sup = (lane == (int)(i & 31)) && bit;
          if (!__any(sup)) remv |= cur[k];
        }
        if (g < 5){
          #pragma unroll
          for (int k = 0; k < 8; k++){ cur[k] = nxt[k]; ci[k] = ni[k]; }
        }
      }
    }
    __syncthreads();
  }

  // ---- epilogue: keep mask -> compaction + zero-fill tail ----
  int nv = (int)nvalid[img];
  if (wave == 0 && lane < 32){
    int cnt2 = (nv > lane) ? (((nv - 1 - lane) >> 5) + 1) : 0;   // #valid q for this word
    ull vm = (cnt2 >= 64) ? ~0ull : ((1ull << cnt2) - 1ull);
    keepP[lane] = (~remv) & vm;
  }
  __syncthreads();
  if (tid < 32){   // permuted -> linear
    ull lin = 0;
    for (int kk = 0; kk < 64; kk++)
      lin |= ((keepP[kk & 31] >> (2 * tid + (kk >> 5))) & 1ull) << kk;
    keepLin[tid] = lin;
    cntArr[tid] = (unsigned)__popcll(lin);
  }
  __syncthreads();
  if (tid < 32){
    unsigned pre = 0;
    for (int w0 = 0; w0 < tid; w0++) pre += cntArr[w0];
    preArr[tid] = pre;
  }
  __syncthreads();
  int totK = (int)(preArr[31] + cntArr[31]);   // total kept
  for (int i = tid; i < PRE; i += 256){
    int w0 = i >> 6, b = i & 63;
    ull kw = keepLin[w0];
    if ((kw >> b) & 1ull){
      unsigned rank = preArr[w0] + (unsigned)__popcll(kw & ((1ull << b) - 1ull));
      if (rank < POST)
        ((float4*)out)[img * POST + rank] = ((const float4*)sorted)[img * PRE + i];
    }
  }
  for (int r = totK + tid; r < POST; r += 256)
    ((float4*)out)[img * POST + r] = make_float4(0.f, 0.f, 0.f, 0.f);
}

extern "C" void kernel_launch(void* const* d_in, const int* in_sizes, int n_in,
                              void* d_out, int out_size, void* d_ws, size_t ws_size,
                              hipStream_t stream){
  const float* cls  = (const float*)d_in[0];
  const float* reg  = (const float*)d_in[1];
  const float* anch = (const float*)d_in[2];
  float* out = (float*)d_out;
  char* ws = (char*)d_ws;

  unsigned* hist1    = (unsigned*)(ws + OFF_HIST1);
  unsigned* stashCnt = (unsigned*)(ws + OFF_STASHC);
  unsigned* candCnt  = (unsigned*)(ws + OFF_CANDCNT);
  unsigned* binCnt   = (unsigned*)(ws + OFF_BINCNT);
  unsigned* b1       = (unsigned*)(ws + OFF_B1);
  unsigned* need1    = (unsigned*)(ws + OFF_NEED1);
  unsigned* nvalid   = (unsigned*)(ws + OFF_NVALID);
  ull*      bitmap   = (ull*)     (ws + OFF_BITMAP);
  unsigned* cand     = (unsigned*)(ws + OFF_CAND);
  ull*      keys     = (ull*)     (ws + OFF_KEYS);
  float*    boxTmp   = (float*)   (ws + OFF_BOXTMP);
  float*    sorted   = (float*)   (ws + OFF_SORTED);
  ull*      maskG    = (ull*)     (ws + OFF_MASK);
  ull*      stash    = (ull*)     (ws + OFF_STASH);
  ull*      binbuf   = (ull*)     (ws + OFF_BINBUF);

  hipMemsetAsync(ws, 0, ZERO_BYTES, stream);

  k_histstash<<<dim3(64, NB), 256, 0, stream>>>(cls, hist1, stash, stashCnt);
  k_scan     <<<NB, 256, 0, stream>>>(hist1, 2000u, b1, need1);
  k_compactS <<<dim3(8, NB), 256, 0, stream>>>(cls, stash, stashCnt, b1, cand, candCnt, binbuf, binCnt);
  k_select   <<<NB, 256, 0, stream>>>(cls, reg, anch, cand, candCnt, binbuf, binCnt,
                                      need1, boxTmp, keys, nvalid);
  k_rank     <<<dim3(8, NB), 256, 0, stream>>>(keys, boxTmp, sorted);
  k_mask     <<<dim3(63, NB), 512, 0, stream>>>(sorted, nvalid, maskG, bitmap);
  k_nms      <<<NB, 256, 0, stream>>>(maskG, bitmap, nvalid, sorted, out);
}

// Round 9
// 301.386 us; speedup vs baseline: 1.1412x; 1.0645x over previous
//
#include <hip/hip_runtime.h>

#define NB 16
#define NN 300000
#define PRE 2000
#define POST 1000

typedef unsigned long long ull;

// ---------- workspace layout (bytes) ----------
static const size_t OFF_HIST1   = 0;                       // 16*1024*4 = 65536
static const size_t OFF_CANDCNT = 65536;                   // 64 (pad 256)
static const size_t OFF_BINCNT  = 65792;                   // 64 (pad 256)
static const size_t OFF_B1      = 66048;
static const size_t OFF_NEED1   = 66304;
static const size_t OFF_NVALID  = 66560;
static const size_t OFF_BITMAP  = 66816;                   // 16*32*8 = 4096
static const size_t ZERO_BYTES  = 70912;                   // memset region
static const size_t OFF_CAND    = 70912;                   // 16*2048*4 = 131072
static const size_t OFF_KEYS    = 201984;                  // 16*2048*8 = 262144
static const size_t OFF_BOXTMP  = 464128;                  // 16*2048*16 = 524288
static const size_t OFF_SORTED  = 988416;                  // 16*2000*16 = 512000
static const size_t OFF_MASK    = 1500416;                 // 16*2000*32*8 = 8192000 (end 9692416)
static const size_t OFF_BINBUF  = OFF_MASK;                // ALIAS: 16*8192*8 = 1MB, consumed by k_select
                                                           // before k_mask writes masks (serial stream)

__device__ __forceinline__ unsigned f2u(float f){
  unsigned b = __float_as_uint(f);
  return (b & 0x80000000u) ? ~b : (b | 0x80000000u);
}

// ---------- pass 1 histogram: top 10 bits (8 replicated LDS copies) ----------
#define H1REP 8
#define H1STRIDE 1025
__global__ void k_hist1(const float* __restrict__ cls, unsigned* __restrict__ hist){
  __shared__ unsigned h[H1REP * H1STRIDE];
  int img = blockIdx.y;
  for (int i = threadIdx.x; i < H1REP * H1STRIDE; i += blockDim.x) h[i] = 0;
  __syncthreads();
  const float* p = cls + (size_t)img * NN;
  int stride = gridDim.x * blockDim.x;
  unsigned rep = (threadIdx.x & (H1REP - 1)) * H1STRIDE;
  for (int i = blockIdx.x * blockDim.x + threadIdx.x; i < NN; i += stride)
    atomicAdd(&h[rep + (f2u(p[i]) >> 22)], 1u);
  __syncthreads();
  unsigned* g = hist + img * 1024;
  for (int i = threadIdx.x; i < 1024; i += blockDim.x){
    unsigned v = 0;
    for (int r = 0; r < H1REP; r++) v += h[r * H1STRIDE + i];
    if (v) atomicAdd(&g[i], v);
  }
}

// ---------- descending rank-select over the 1024-bin histogram ----------
__global__ void k_scan(const unsigned* __restrict__ hist, int bins,
                       unsigned K0,
                       unsigned* __restrict__ outBin, unsigned* __restrict__ outNeed){
  int img = blockIdx.x;
  int t = threadIdx.x;
  const unsigned* hh = hist + img * bins;
  unsigned K = K0;
  int per = bins >> 8;
  unsigned s = 0;
  for (int q = 0; q < per; q++) s += hh[bins - 1 - (t * per + q)];
  __shared__ unsigned arr[256];
  arr[t] = s;
  __syncthreads();
  for (int off = 1; off < 256; off <<= 1){
    unsigned v = (t >= off) ? arr[t - off] : 0u;
    __syncthreads();
    arr[t] += v;
    __syncthreads();
  }
  unsigned incl = arr[t], excl = incl - s;
  if (excl < K && K <= incl){
    unsigned c = excl;
    for (int q = 0; q < per; q++){
      int b = bins - 1 - (t * per + q);
      unsigned cnt = hh[b];
      if (c + cnt >= K){ outBin[img] = (unsigned)b; outNeed[img] = K - c; break; }
      c += cnt;
    }
  }
}

// ---------- compaction: top10 > b1 -> cand ; top10 == b1 -> binbuf (LDS-aggregated) ----------
__global__ void k_compactA(const float* __restrict__ cls, const unsigned* __restrict__ b1,
                           unsigned* __restrict__ cand, unsigned* __restrict__ candCnt,
                           ull* __restrict__ binbuf, unsigned* __restrict__ binCnt){
  __shared__ unsigned lc[1024];
  __shared__ ull lb[512];
  __shared__ unsigned lcn, lbn, baseC, baseB;
  int img = blockIdx.y;
  if (threadIdx.x == 0){ lcn = 0; lbn = 0; }
  __syncthreads();
  unsigned bb1 = b1[img];
  const float* p = cls + (size_t)img * NN;
  int stride = gridDim.x * blockDim.x;
  for (int i = blockIdx.x * blockDim.x + threadIdx.x; i < NN; i += stride){
    unsigned u = f2u(p[i]);
    unsigned top = u >> 22;
    if (top > bb1){
      unsigned pos = atomicAdd(&lcn, 1u);
      if (pos < 1024u) lc[pos] = (unsigned)i;
      else { unsigned g = atomicAdd(&candCnt[img], 1u); if (g < 2048u) cand[img * 2048 + g] = (unsigned)i; }
    } else if (top == bb1){
      ull e = ((ull)u << 32) | (unsigned)i;
      unsigned pos = atomicAdd(&lbn, 1u);
      if (pos < 512u) lb[pos] = e;
      else { unsigned g = atomicAdd(&binCnt[img], 1u); if (g < 8192u) binbuf[img * 8192 + g] = e; }
    }
  }
  __syncthreads();
  unsigned nc = lcn < 1024u ? lcn : 1024u;
  unsigned nb = lbn < 512u ? lbn : 512u;
  if (threadIdx.x == 0){
    if (nc) baseC = atomicAdd(&candCnt[img], nc);
    if (nb) baseB = atomicAdd(&binCnt[img], nb);
  }
  __syncthreads();
  for (unsigned t = threadIdx.x; t < nc; t += blockDim.x){
    unsigned g = baseC + t;
    if (g < 2048u) cand[img * 2048 + g] = lc[t];
  }
  for (unsigned t = threadIdx.x; t < nb; t += blockDim.x){
    unsigned g = baseB + t;
    if (g < 8192u) binbuf[img * 8192 + g] = lb[t];
  }
}

// ---------- in-LDS 2-level refinement over bin b1 (~6400 entries) + tie-rank + fused decode ----------
__global__ __launch_bounds__(256) void k_select(const float* __restrict__ cls,
                                                const float* __restrict__ reg,
                                                const float* __restrict__ anch,
                                                unsigned* __restrict__ cand,
                                                const unsigned* __restrict__ candCnt,
                                                const ull* __restrict__ binbuf,
                                                const unsigned* __restrict__ binCnt,
                                                const unsigned* __restrict__ need1,
                                                float* __restrict__ boxTmp,
                                                ull* __restrict__ keys,
                                                unsigned* __restrict__ nvalid){
  __shared__ unsigned hist[2048];
  __shared__ unsigned arr[256];
  __shared__ unsigned b2s, need2s, b3s, need3s;
  __shared__ unsigned tiePos[1024];
  __shared__ unsigned wcnt, tieCnt;
  int img = blockIdx.x, tid = threadIdx.x;
  unsigned bc = binCnt[img]; if (bc > 8192u) bc = 8192u;
  unsigned base = candCnt[img];
  unsigned need = need1[img];
  const ull* bb = binbuf + img * 8192;

  if (tid == 0){ wcnt = 0; tieCnt = 0; b2s = 0; need2s = 0; b3s = 0; need3s = 0; }
  // ---- S1: hist of bits 21..11 ----
  for (int i = tid; i < 2048; i += 256) hist[i] = 0;
  __syncthreads();
  for (unsigned t = tid; t < bc; t += 256){
    unsigned u = (unsigned)(bb[t] >> 32);
    atomicAdd(&hist[(u >> 11) & 0x7FFu], 1u);
  }
  __syncthreads();
  {
    unsigned s = 0;
    for (int q = 0; q < 8; q++) s += hist[2047 - (tid * 8 + q)];
    arr[tid] = s; __syncthreads();
    for (int off = 1; off < 256; off <<= 1){
      unsigned v = (tid >= off) ? arr[tid - off] : 0u;
      __syncthreads(); arr[tid] += v; __syncthreads();
    }
    unsigned incl = arr[tid], excl = incl - s;
    if (excl < need && need <= incl){
      unsigned c = excl;
      for (int q = 0; q < 8; q++){
        int b = 2047 - (tid * 8 + q);
        unsigned cnt = hist[b];
        if (c + cnt >= need){ b2s = (unsigned)b; need2s = need - c; break; }
        c += cnt;
      }
    }
  }
  __syncthreads();
  unsigned b2 = b2s, need2 = need2s;
  // ---- S2: hist of bits 10..0 where mid == b2 ----
  for (int i = tid; i < 2048; i += 256) hist[i] = 0;
  __syncthreads();
  for (unsigned t = tid; t < bc; t += 256){
    unsigned u = (unsigned)(bb[t] >> 32);
    if (((u >> 11) & 0x7FFu) == b2) atomicAdd(&hist[u & 0x7FFu], 1u);
  }
  __syncthreads();
  {
    unsigned s = 0;
    for (int q = 0; q < 8; q++) s += hist[2047 - (tid * 8 + q)];
    arr[tid] = s; __syncthreads();
    for (int off = 1; off < 256; off <<= 1){
      unsigned v = (tid >= off) ? arr[tid - off] : 0u;
      __syncthreads(); arr[tid] += v; __syncthreads();
    }
    unsigned incl = arr[tid], excl = incl - s;
    if (excl < need2 && need2 <= incl){
      unsigned c = excl;
      for (int q = 0; q < 8; q++){
        int b = 2047 - (tid * 8 + q);
        unsigned cnt = hist[b];
        if (c + cnt >= need2){ b3s = (unsigned)b; need3s = need2 - c; break; }
        c += cnt;
      }
    }
  }
  __syncthreads();
  unsigned b3 = b3s, need3 = need3s;
  // ---- S3: write takes, collect ties ----
  for (unsigned t = tid; t < bc; t += 256){
    ull e = bb[t];
    unsigned u = (unsigned)(e >> 32);
    unsigned mid = (u >> 11) & 0x7FFu, low = u & 0x7FFu;
    bool take = (mid > b2) || (mid == b2 && low > b3);
    bool tie  = (mid == b2) && (low == b3);
    if (take){
      unsigned p = atomicAdd(&wcnt, 1u);
      unsigned g = base + p;
      if (g < 2048u) cand[img * 2048 + g] = (unsigned)(e & 0xFFFFFFFFull);
    } else if (tie){
      unsigned p = atomicAdd(&tieCnt, 1u);
      if (p < 1024u) tiePos[p] = t;
    }
  }
  __syncthreads();
  unsigned above = wcnt;                 // == need - need3
  unsigned ec = tieCnt; if (ec > 1024u) ec = 1024u;
  // rank ties by index asc, keep the need3 smallest (order within cand irrelevant: keys fix it)
  for (unsigned t = tid; t < ec; t += 256){
    unsigned idx = (unsigned)(bb[tiePos[t]] & 0xFFFFFFFFull);
    unsigned r = 0;
    for (unsigned s = 0; s < ec; s++){
      unsigned idx2 = (unsigned)(bb[tiePos[s]] & 0xFFFFFFFFull);
      r += (idx2 < idx) ? 1u : 0u;
    }
    if (r < need3){
      unsigned g = base + above + r;
      if (g < 2048u) cand[img * 2048 + g] = idx;
    }
  }
  __syncthreads();
  // ---- fused decode + clip + validity + key for all 2048 slots of this image ----
  for (int slot = tid; slot < 2048; slot += 256){
    ull key = 0ull;
    float4 box = make_float4(0.f, 0.f, 0.f, 0.f);
    bool counted = false;
    if (slot < PRE){
      unsigned i = cand[img * 2048 + slot];
      if (i < NN){
        size_t gi = (size_t)img * NN + i;
        float4 a = ((const float4*)anch)[gi];
        float4 r = ((const float4*)reg)[gi];
        float sc2 = cls[gi];
        float aw = a.z - a.x, ah = a.w - a.y;
        float acx = a.x + 0.5f * aw, acy = a.y + 0.5f * ah;
        float pcx = r.x * aw + acx, pcy = r.y * ah + acy;
        float pw = expf(r.z) * aw, ph = expf(r.w) * ah;
        float x1 = pcx - 0.5f * pw, y1 = pcy - 0.5f * ph;
        float x2 = pcx + 0.5f * pw, y2 = pcy + 0.5f * ph;
        x1 = fminf(fmaxf(x1, 0.f), 1333.f); x2 = fminf(fmaxf(x2, 0.f), 1333.f);
        y1 = fminf(fmaxf(y1, 0.f), 800.f);  y2 = fminf(fmaxf(y2, 0.f), 800.f);
        bool valid = ((x2 - x1) >= 0.001f) && ((y2 - y1) >= 0.001f);
        unsigned up = valid ? f2u(sc2) : 0u;
        key = ((ull)up << 32) | (ull)(0xFFFFFFFFu - i);   // score desc, index asc
        box = make_float4(x1, y1, x2, y2);
        counted = valid;
      }
    }
    keys[img * 2048 + slot] = key;
    ((float4*)boxTmp)[img * 2048 + slot] = box;
    ull bal = __ballot(counted);
    if ((tid & 63) == 0 && bal)
      atomicAdd(&nvalid[img], (unsigned)__popcll(bal));
  }
}

// ---------- rank-by-counting sort: rank = #{j : key_j > key_e}; scatter ----------
__global__ __launch_bounds__(256) void k_rank(const ull* __restrict__ keys,
                                              const float* __restrict__ boxTmp,
                                              float* __restrict__ sorted){
  __shared__ ull lk[2048];
  int img = blockIdx.y;
  int e = blockIdx.x * 256 + threadIdx.x;
  for (int t = threadIdx.x; t < 2048; t += 256) lk[t] = keys[img * 2048 + t];
  __syncthreads();
  ull me = lk[e];
  unsigned rank = 0;
  #pragma unroll 8
  for (int j = 0; j < 2048; j++) rank += (lk[j] > me) ? 1u : 0u;
  if (rank < PRE)
    ((float4*)sorted)[img * PRE + rank] = ((const float4*)boxTmp)[img * 2048 + e];
}

// ---------- suppression bitmask, PERMUTED layout: word w bit q <-> j = 32q+w ----------
// Triangular load balance (verified R6): unit owns front row f and mirror PRE-1-f,
// constant ~63 q-iters/unit. Grid 63x16 ~ 4 blocks/CU (LDS limit), uniform drain.
__global__ __launch_bounds__(512) void k_mask(const float* __restrict__ sorted,
                                              const unsigned* __restrict__ nvalid,
                                              ull* __restrict__ mask, ull* __restrict__ bitmap){
  __shared__ float4 bx[PRE];
  __shared__ float  ar[PRE];
  int img = blockIdx.y, tid = threadIdx.x;
  int jmin = blockIdx.x * 16;
  for (int i = jmin + tid; i < PRE; i += 512){
    float4 b = ((const float4*)sorted)[img * PRE + i];
    bx[i] = b;
    ar[i] = (b.z - b.x) * (b.w - b.y);
  }
  __syncthreads();
  int unit = tid >> 5;                       // 0..15
  int w = tid & 31;
  int lane = tid & 63;
  int nv = (int)nvalid[img];
  int qhi = ((PRE - 1 - w) >> 5) + 1;
  int rowF = jmin + unit;                    // front row in [0, 1008)
  #pragma unroll
  for (int rr = 0; rr < 2; rr++){
    int row = (rr == 0) ? rowF : (PRE - 1 - rowF);   // mirror pair (middle overlap benign)
    float4 bi = bx[row];
    float ai = ar[row];
    int qlo = (row >= w) ? (((row - w) >> 5) + 1) : 0;
    ull m = 0;
    for (int q = qlo; q < qhi; q++){
      int j = (q << 5) + w;
      float4 bj = bx[j];
      float xx1 = fmaxf(bi.x, bj.x), yy1 = fmaxf(bi.y, bj.y);
      float xx2 = fminf(bi.z, bj.z), yy2 = fminf(bi.w, bj.w);
      float ww = fmaxf(xx2 - xx1, 0.f), hh = fmaxf(yy2 - yy1, 0.f);
      float inter = ww * hh;
      float uni = ai + ar[j] - inter;
      if (inter / fmaxf(uni, 1e-8f) > 0.7f) m |= (1ull << q);   // exact div (bit-match)
    }
    mask[((size_t)(img * PRE + row)) * 32 + w] = m;
    ull nz = __ballot(m != 0ull);            // wave = 2 units; halves are per-unit rows
    if (lane == 0 || lane == 32){
      ull half = (lane == 0) ? (nz & 0xFFFFFFFFull) : (nz >> 32);
      if (half && row < nv)
        atomicOr(&bitmap[img * 32 + (row >> 6)], 1ull << (row & 63));
    }
  }
}

// ---------- serial NMS scan (latency-optimized) + rank/scatter + zero-fill tail ----------
#define CHR 48
__global__ __launch_bounds__(256) void k_nms(const ull* __restrict__ mask,
                                             const ull* __restrict__ bitmap,
                                             const unsigned* __restrict__ nvalid,
                                             const float* __restrict__ sorted,
                                             float* __restrict__ out){
  __shared__ unsigned rowsLds[2048];
  __shared__ unsigned cntw[32];
  __shared__ unsigned wbaseS[32];
  __shared__ int mcountS, mpS;
  __shared__ ull cacheD[2][CHR * 32];
  __shared__ ull keepP[32];     // permuted keep: word w bit q -> j = 32q+w
  __shared__ ull keepLin[32];   // linear keep:   word w bit b -> i = 64w+b
  __shared__ unsigned cntArr[32], preArr[32];
  int img = blockIdx.x, tid = threadIdx.x;
  int lane = tid & 63, wave = tid >> 6;

  // ---- phase A: parallel ordered row-list build ----
  if (tid < 32) cntw[tid] = (unsigned)__popcll(bitmap[img * 32 + tid]);
  __syncthreads();
  if (tid == 0){
    unsigned s = 0;
    for (int w0 = 0; w0 < 32; w0++){ wbaseS[w0] = s; s += cntw[w0]; }
    mcountS = (int)s;
    mpS = ((int)s + CHR - 1) / CHR * CHR;
  }
  __syncthreads();
  int m = mcountS, mp = mpS;
  if (tid < 32){
    ull bits = bitmap[img * 32 + tid];
    unsigned pos = wbaseS[tid];
    int base_i = tid * 64;
    while (bits){
      int b = __ffsll((long long)bits) - 1;
      rowsLds[pos++] = (unsigned)(base_i + b);
      bits &= bits - 1;
    }
  }
  for (int t = m + tid; t < mp; t += 256) rowsLds[t] = PRE - 1;  // zero-mask pad row
  __syncthreads();

  // ---- phase B: double-buffered staged serial scan ----
  int nch = mp / CHR;
  ull remv = 0;
  const ull* mg = mask + (size_t)img * PRE * 32;

  if (nch > 0 && tid >= 64){
    int s = tid - 64;
    ull v[8];
    #pragma unroll
    for (int k = 0; k < 8; k++){
      int t = k * 192 + s;                 // 0..1535 = 48 rows * 32 words
      unsigned rr = rowsLds[t >> 5];
      v[k] = mg[(size_t)rr * 32 + (t & 31)];
    }
    #pragma unroll
    for (int k = 0; k < 8; k++) cacheD[0][k * 192 + s] = v[k];
  }
  __syncthreads();

  for (int c = 0; c < nch; c++){
    int cb = c & 1;
    if (tid >= 64){
      if (c + 1 < nch){
        int q0n = (c + 1) * CHR;
        int s = tid - 64;
        ull v[8];
        #pragma unroll
        for (int k = 0; k < 8; k++){
          int t = k * 192 + s;
          unsigned rr = rowsLds[q0n + (t >> 5)];
          v[k] = mg[(size_t)rr * 32 + (t & 31)];
        }
        #pragma unroll
        for (int k = 0; k < 8; k++) cacheD[cb ^ 1][k * 192 + s] = v[k];
      }
    } else {
      // wave 0: serial scan of 48 rows, pipelined 8 ahead
      const ull* cbuf = cacheD[cb];
      const int q0 = c * CHR;
      ull cur[8]; unsigned ci[8];
      #pragma unroll
      for (int k = 0; k < 8; k++){
        ci[k] = rowsLds[q0 + k];
        cur[k] = cbuf[(k << 5) | (lane & 31)];
      }
      #pragma unroll
      for (int g = 0; g < 6; g++){
        ull nxt[8]; unsigned ni[8];
        if (g < 5){
          #pragma unroll
          for (int k = 0; k < 8; k++){
            int lq = (g + 1) * 8 + k;
            ni[k] = rowsLds[q0 + lq];
            nxt[k] = cbuf[(lq << 5) | (lane & 31)];
          }
        }
        #pragma unroll
        for (int k = 0; k < 8; k++){
          unsigned i = ci[k];
          unsigned bit = ((unsigned)(remv >> (i >> 5))) & 1u;
          int sup = (lane == (int)(i & 31)) && bit;
          if (!__any(sup)) remv |= cur[k];
        }
        if (g < 5){
          #pragma unroll
          for (int k = 0; k < 8; k++){ cur[k] = nxt[k]; ci[k] = ni[k]; }
        }
      }
    }
    __syncthreads();
  }

  // ---- epilogue: keep mask -> compaction + zero-fill tail ----
  int nv = (int)nvalid[img];
  if (wave == 0 && lane < 32){
    int cnt2 = (nv > lane) ? (((nv - 1 - lane) >> 5) + 1) : 0;   // #valid q for this word
    ull vm = (cnt2 >= 64) ? ~0ull : ((1ull << cnt2) - 1ull);
    keepP[lane] = (~remv) & vm;
  }
  __syncthreads();
  if (tid < 32){   // permuted -> linear
    ull lin = 0;
    for (int kk = 0; kk < 64; kk++)
      lin |= ((keepP[kk & 31] >> (2 * tid + (kk >> 5))) & 1ull) << kk;
    keepLin[tid] = lin;
    cntArr[tid] = (unsigned)__popcll(lin);
  }
  __syncthreads();
  if (tid < 32){
    unsigned pre = 0;
    for (int w0 = 0; w0 < tid; w0++) pre += cntArr[w0];
    preArr[tid] = pre;
  }
  __syncthreads();
  int totK = (int)(preArr[31] + cntArr[31]);   // total kept
  for (int i = tid; i < PRE; i += 256){
    int w0 = i >> 6, b = i & 63;
    ull kw = keepLin[w0];
    if ((kw >> b) & 1ull){
      unsigned rank = preArr[w0] + (unsigned)__popcll(kw & ((1ull << b) - 1ull));
      if (rank < POST)
        ((float4*)out)[img * POST + rank] = ((const float4*)sorted)[img * PRE + i];
    }
  }
  for (int r = totK + tid; r < POST; r += 256)
    ((float4*)out)[img * POST + r] = make_float4(0.f, 0.f, 0.f, 0.f);
}

extern "C" void kernel_launch(void* const* d_in, const int* in_sizes, int n_in,
                              void* d_out, int out_size, void* d_ws, size_t ws_size,
                              hipStream_t stream){
  const float* cls  = (const float*)d_in[0];
  const float* reg  = (const float*)d_in[1];
  const float* anch = (const float*)d_in[2];
  float* out = (float*)d_out;
  char* ws = (char*)d_ws;

  unsigned* hist1   = (unsigned*)(ws + OFF_HIST1);
  unsigned* candCnt = (unsigned*)(ws + OFF_CANDCNT);
  unsigned* binCnt  = (unsigned*)(ws + OFF_BINCNT);
  unsigned* b1      = (unsigned*)(ws + OFF_B1);
  unsigned* need1   = (unsigned*)(ws + OFF_NEED1);
  unsigned* nvalid  = (unsigned*)(ws + OFF_NVALID);
  ull*      bitmap  = (ull*)     (ws + OFF_BITMAP);
  unsigned* cand    = (unsigned*)(ws + OFF_CAND);
  ull*      keys    = (ull*)     (ws + OFF_KEYS);
  float*    boxTmp  = (float*)   (ws + OFF_BOXTMP);
  float*    sorted  = (float*)   (ws + OFF_SORTED);
  ull*      maskG   = (ull*)     (ws + OFF_MASK);
  ull*      binbuf  = (ull*)     (ws + OFF_BINBUF);

  hipMemsetAsync(ws, 0, ZERO_BYTES, stream);

  k_hist1   <<<dim3(64, NB), 256, 0, stream>>>(cls, hist1);
  k_scan    <<<NB, 256, 0, stream>>>(hist1, 1024, 2000u, b1, need1);
  k_compactA<<<dim3(64, NB), 256, 0, stream>>>(cls, b1, cand, candCnt, binbuf, binCnt);
  k_select  <<<NB, 256, 0, stream>>>(cls, reg, anch, cand, candCnt, binbuf, binCnt,
                                     need1, boxTmp, keys, nvalid);
  k_rank    <<<dim3(8, NB), 256, 0, stream>>>(keys, boxTmp, sorted);
  k_mask    <<<dim3(63, NB), 512, 0, stream>>>(sorted, nvalid, maskG, bitmap);
  k_nms     <<<NB, 256, 0, stream>>>(maskG, bitmap, nvalid, sorted, out);
}